// Round 1
// baseline (866.043 us; speedup 1.0000x reference)
//
#include <hip/hip_runtime.h>
#include <hip/hip_bf16.h>

// StructuralEncoder: gather(3x128 f32) -> 384->256->256->128 MLP (relu,relu,linear)
// -> mean over 1M rows -> 128->256->128 head.
// Strategy: fused bf16 MFMA per 64-row block, transposed compute (h^T = W^T x^T),
// XOR-swizzled LDS activations, biases folded into acc init, per-block partial
// sums -> 128 atomic buckets -> tiny f32 head kernel.

#define EMBED 128
#define HID 256
#define BM 64
#define NBUCKET 128

typedef __bf16 bf16x8 __attribute__((ext_vector_type(8)));
typedef __bf16 bf16x4 __attribute__((ext_vector_type(4)));
typedef float f32x4 __attribute__((ext_vector_type(4)));

// ---- prep: transpose + convert weights to bf16, dst[n*K+k] = src[k*N+n] ----
__global__ void transpose_cvt(const float* __restrict__ src, __bf16* __restrict__ dst,
                              int K, int N) {
    int idx = blockIdx.x * 256 + threadIdx.x;
    if (idx >= K * N) return;
    int nI = idx / K;
    int k  = idx - nI * K;
    dst[idx] = (__bf16)src[k * N + nI];
}

// ---- main fused MLP over 64-row tiles ----
__global__ __launch_bounds__(256, 2) void mlp_main(
    const int* __restrict__ triples,
    const float* __restrict__ ent, const float* __restrict__ rel,
    const __bf16* __restrict__ W1t, const float* __restrict__ b1,
    const __bf16* __restrict__ W2t, const float* __restrict__ b2,
    const __bf16* __restrict__ W3t,
    float* __restrict__ part, int n)
{
    // LDS: region0 [0,32KB): xs (16KB, layer1) then h2s (32KB, layer3 input)
    //      region1 [32KB,64KB): h1s
    __shared__ unsigned char lds[65536];
    unsigned char* xs  = lds;          // 64 x 128 bf16, stride 256B, swizzled
    unsigned char* h1s = lds + 32768;  // 64 x 256 bf16, stride 512B, swizzled
    unsigned char* h2s = lds;          // 64 x 256 bf16, stride 512B, swizzled

    const int tid  = threadIdx.x;
    const int wave = tid >> 6;
    const int lane = tid & 63;
    const int l15  = lane & 15;
    const int l4   = lane >> 4;
    const int s0   = blockIdx.x * BM;

    // ================= Layer 1: h1 = relu(x @ W1 + b1) =================
    f32x4 acc[4][4];
    {
        const int fb = wave * 64;
        for (int m = 0; m < 4; m++) {
            f32x4 bias = *(const f32x4*)(b1 + fb + m * 16 + l4 * 4);
            for (int nn = 0; nn < 4; nn++) acc[m][nn] = bias;
        }
    }
    for (int c = 0; c < 3; c++) {
        // stage 64x128 f32 gather -> bf16 LDS (swizzled)
        {
            const float* tbl = (c == 1) ? rel : ent;
            const int scol = (tid & 15) * 8;
            for (int pass = 0; pass < 4; pass++) {
                int s = pass * 16 + (tid >> 4);
                int g = s0 + s;
                int row = triples[(g < n ? g : 0) * 3 + c];
                const float* src = tbl + row * EMBED + scol;
                float4 v0 = *(const float4*)(src);
                float4 v1 = *(const float4*)(src + 4);
                bf16x8 w;
                w[0] = (__bf16)v0.x; w[1] = (__bf16)v0.y;
                w[2] = (__bf16)v0.z; w[3] = (__bf16)v0.w;
                w[4] = (__bf16)v1.x; w[5] = (__bf16)v1.y;
                w[6] = (__bf16)v1.z; w[7] = (__bf16)v1.w;
                int off = (s * 256 + scol * 2) ^ ((s & 7) << 4);
                *(bf16x8*)(xs + off) = w;
            }
        }
        __syncthreads();
        const __bf16* Wc = W1t + (wave * 64 + l15) * 384 + c * 128 + l4 * 8;
        for (int kk = 0; kk < 4; kk++) {
            bf16x8 bfr[4];
            for (int nn = 0; nn < 4; nn++) {
                int s = nn * 16 + l15;
                int off = (s * 256 + (kk * 32 + l4 * 8) * 2) ^ ((s & 7) << 4);
                bfr[nn] = *(const bf16x8*)(xs + off);
            }
            bf16x8 afr[4];
            for (int m = 0; m < 4; m++)
                afr[m] = *(const bf16x8*)(Wc + m * 16 * 384 + kk * 32);
            for (int m = 0; m < 4; m++)
                for (int nn = 0; nn < 4; nn++)
                    acc[m][nn] = __builtin_amdgcn_mfma_f32_16x16x32_bf16(
                        afr[m], bfr[nn], acc[m][nn], 0, 0, 0);
        }
        __syncthreads();
    }
    // write h1 (relu, bf16, packed 4) to h1s
    for (int m = 0; m < 4; m++) {
        int f0 = wave * 64 + m * 16 + l4 * 4;
        for (int nn = 0; nn < 4; nn++) {
            int s = nn * 16 + l15;
            bf16x4 p;
            for (int j = 0; j < 4; j++) {
                float v = acc[m][nn][j];
                p[j] = (__bf16)(v > 0.f ? v : 0.f);
            }
            int off = (s * 512 + f0 * 2) ^ ((s & 7) << 4);
            *(bf16x4*)(h1s + off) = p;
        }
    }
    __syncthreads();

    // ================= Layer 2: h2 = relu(h1 @ W2 + b2) =================
    f32x4 acc2[4][4];
    {
        const int fb = wave * 64;
        for (int m = 0; m < 4; m++) {
            f32x4 bias = *(const f32x4*)(b2 + fb + m * 16 + l4 * 4);
            for (int nn = 0; nn < 4; nn++) acc2[m][nn] = bias;
        }
    }
    {
        const __bf16* Wc = W2t + (wave * 64 + l15) * 256 + l4 * 8;
        for (int kk = 0; kk < 8; kk++) {
            bf16x8 bfr[4];
            for (int nn = 0; nn < 4; nn++) {
                int s = nn * 16 + l15;
                int off = (s * 512 + (kk * 32 + l4 * 8) * 2) ^ ((s & 7) << 4);
                bfr[nn] = *(const bf16x8*)(h1s + off);
            }
            bf16x8 afr[4];
            for (int m = 0; m < 4; m++)
                afr[m] = *(const bf16x8*)(Wc + m * 16 * 256 + kk * 32);
            for (int m = 0; m < 4; m++)
                for (int nn = 0; nn < 4; nn++)
                    acc2[m][nn] = __builtin_amdgcn_mfma_f32_16x16x32_bf16(
                        afr[m], bfr[nn], acc2[m][nn], 0, 0, 0);
        }
    }
    __syncthreads();  // all layer-2 reads of h1s done; h2s overlaps region0 (xs dead)
    for (int m = 0; m < 4; m++) {
        int f0 = wave * 64 + m * 16 + l4 * 4;
        for (int nn = 0; nn < 4; nn++) {
            int s = nn * 16 + l15;
            bf16x4 p;
            for (int j = 0; j < 4; j++) {
                float v = acc2[m][nn][j];
                p[j] = (__bf16)(v > 0.f ? v : 0.f);
            }
            int off = (s * 512 + f0 * 2) ^ ((s & 7) << 4);
            *(bf16x4*)(h2s + off) = p;
        }
    }
    __syncthreads();

    // ================= Layer 3: enc = h2 @ W3 (bias deferred to head) ======
    f32x4 acc3[2][4];
    for (int m = 0; m < 2; m++)
        for (int nn = 0; nn < 4; nn++)
            acc3[m][nn] = (f32x4)(0.f);
    {
        const __bf16* Wc = W3t + (wave * 32 + l15) * 256 + l4 * 8;
        for (int kk = 0; kk < 8; kk++) {
            bf16x8 bfr[4];
            for (int nn = 0; nn < 4; nn++) {
                int s = nn * 16 + l15;
                int off = (s * 512 + (kk * 32 + l4 * 8) * 2) ^ ((s & 7) << 4);
                bfr[nn] = *(const bf16x8*)(h2s + off);
            }
            bf16x8 afr[2];
            for (int m = 0; m < 2; m++)
                afr[m] = *(const bf16x8*)(Wc + m * 16 * 256 + kk * 32);
            for (int m = 0; m < 2; m++)
                for (int nn = 0; nn < 4; nn++)
                    acc3[m][nn] = __builtin_amdgcn_mfma_f32_16x16x32_bf16(
                        afr[m], bfr[nn], acc3[m][nn], 0, 0, 0);
        }
    }
    // reduce over samples, accumulate into bucket
    {
        float* bucket = part + (blockIdx.x & (NBUCKET - 1)) * 128;
        for (int m = 0; m < 2; m++) {
            for (int j = 0; j < 4; j++) {
                float v = 0.f;
                for (int nn = 0; nn < 4; nn++) {
                    int g = s0 + nn * 16 + l15;
                    float t = acc3[m][nn][j];
                    v += (g < n) ? t : 0.f;
                }
                for (int off = 1; off < 16; off <<= 1) v += __shfl_xor(v, off);
                if (l15 == 0) {
                    int f = wave * 32 + m * 16 + l4 * 4 + j;
                    atomicAdd(bucket + f, v);
                }
            }
        }
    }
}

// ---- head: agg = sum/n + b3; out = relu(agg@Wf1+bf1)@Wf2+bf2 (f32) ----
__global__ void head_kernel(const float* __restrict__ part, const float* __restrict__ b3,
                            const float* __restrict__ Wf1, const float* __restrict__ bf1,
                            const float* __restrict__ Wf2, const float* __restrict__ bf2,
                            float* __restrict__ out, int n)
{
    __shared__ float agg[128];
    __shared__ float t[256];
    const int tid = threadIdx.x;
    if (tid < 128) {
        float s = 0.f;
        for (int b = 0; b < NBUCKET; b++) s += part[b * 128 + tid];
        agg[tid] = s / (float)n + b3[tid];
    }
    __syncthreads();
    {
        float a = bf1[tid];
        for (int k = 0; k < 128; k++) a += agg[k] * Wf1[k * 256 + tid];
        t[tid] = a > 0.f ? a : 0.f;
    }
    __syncthreads();
    if (tid < 128) {
        float o = bf2[tid];
        for (int i = 0; i < 256; i++) o += t[i] * Wf2[i * 128 + tid];
        out[tid] = o;
    }
}

extern "C" void kernel_launch(void* const* d_in, const int* in_sizes, int n_in,
                              void* d_out, int out_size, void* d_ws, size_t ws_size,
                              hipStream_t stream) {
    const int*   triples = (const int*)d_in[0];
    const float* ent     = (const float*)d_in[1];
    const float* rel     = (const float*)d_in[2];
    const float* W1      = (const float*)d_in[3];
    const float* b1      = (const float*)d_in[4];
    const float* W2      = (const float*)d_in[5];
    const float* b2      = (const float*)d_in[6];
    const float* W3      = (const float*)d_in[7];
    const float* b3      = (const float*)d_in[8];
    const float* Wf1     = (const float*)d_in[9];
    const float* bf1     = (const float*)d_in[10];
    const float* Wf2     = (const float*)d_in[11];
    const float* bf2     = (const float*)d_in[12];
    float* out = (float*)d_out;
    const int n = in_sizes[0] / 3;

    // ws layout (bytes): W1t[0,196608) W2t[196608,327680) W3t[327680,393216)
    //                    part[393216,458752)  — total 448 KB
    __bf16* W1t = (__bf16*)d_ws;
    __bf16* W2t = (__bf16*)((char*)d_ws + 196608);
    __bf16* W3t = (__bf16*)((char*)d_ws + 327680);
    float*  prt = (float*)((char*)d_ws + 393216);

    transpose_cvt<<<(384 * 256 + 255) / 256, 256, 0, stream>>>(W1, W1t, 384, 256);
    transpose_cvt<<<(256 * 256 + 255) / 256, 256, 0, stream>>>(W2, W2t, 256, 256);
    transpose_cvt<<<(256 * 128 + 255) / 256, 256, 0, stream>>>(W3, W3t, 256, 128);
    hipMemsetAsync(prt, 0, NBUCKET * 128 * sizeof(float), stream);

    const int blocks = (n + BM - 1) / BM;
    mlp_main<<<blocks, 256, 0, stream>>>(triples, ent, rel, W1t, b1, W2t, b2, W3t, prt, n);
    head_kernel<<<1, 256, 0, stream>>>(prt, b3, Wf1, bf1, Wf2, bf2, out, n);
}

// Round 2
// 777.572 us; speedup vs baseline: 1.1138x; 1.1138x over previous
//
#include <hip/hip_runtime.h>
#include <hip/hip_bf16.h>

// StructuralEncoder: gather(3x128 f32) -> 384->256->256->128 MLP (relu,relu,linear)
// -> mean over 1M rows -> 128->256->128 head.
// R2: 48KB LDS (3 blocks/CU), register-pipelined gather (issue next-c loads
// before current-c MFMA), setprio around MFMA clusters.

#define EMBED 128
#define HID 256
#define BM 64
#define NBUCKET 128

typedef __bf16 bf16x8 __attribute__((ext_vector_type(8)));
typedef __bf16 bf16x4 __attribute__((ext_vector_type(4)));
typedef float f32x4 __attribute__((ext_vector_type(4)));

// ---- prep: transpose + convert weights to bf16, dst[n*K+k] = src[k*N+n] ----
__global__ void transpose_cvt(const float* __restrict__ src, __bf16* __restrict__ dst,
                              int K, int N) {
    int idx = blockIdx.x * 256 + threadIdx.x;
    if (idx >= K * N) return;
    int nI = idx / K;
    int k  = idx - nI * K;
    dst[idx] = (__bf16)src[k * N + nI];
}

// ---- main fused MLP over 64-row tiles ----
__global__ __launch_bounds__(256, 3) void mlp_main(
    const int* __restrict__ triples,
    const float* __restrict__ ent, const float* __restrict__ rel,
    const __bf16* __restrict__ W1t, const float* __restrict__ b1,
    const __bf16* __restrict__ W2t, const float* __restrict__ b2,
    const __bf16* __restrict__ W3t,
    float* __restrict__ part, int n)
{
    // LDS 48KB: xs [0,16K) 64x128 bf16 swizzled; h1s [16K,48K) 64x256 bf16
    // swizzled; h2s overwrites h1s after layer-2 reads complete.
    __shared__ unsigned char lds[49152];
    unsigned char* xs  = lds;
    unsigned char* h1s = lds + 16384;
    unsigned char* h2s = h1s;

    const int tid  = threadIdx.x;
    const int wave = tid >> 6;
    const int lane = tid & 63;
    const int l15  = lane & 15;
    const int l4   = lane >> 4;
    const int s0   = blockIdx.x * BM;

    const int sp   = tid >> 4;        // 0..15: sample subgroup for staging
    const int scol = (tid & 15) * 8;  // float column chunk for staging

    // ---- prologue: triple indices + issue c0 row loads ----
    int rows[3][4];
    for (int p = 0; p < 4; p++) {
        int g = s0 + p * 16 + sp;
        const int* t = triples + (g < n ? g : 0) * 3;
        rows[0][p] = t[0]; rows[1][p] = t[1]; rows[2][p] = t[2];
    }
    float4 pa[4], pb[4];
    for (int p = 0; p < 4; p++) {
        const float* src = ent + rows[0][p] * EMBED + scol;
        pa[p] = *(const float4*)src;
        pb[p] = *(const float4*)(src + 4);
    }

    // ================= Layer 1: h1 = relu(x @ W1 + b1) =================
    f32x4 acc[4][4];
    {
        const int fb = wave * 64;
        for (int m = 0; m < 4; m++) {
            f32x4 bias = *(const f32x4*)(b1 + fb + m * 16 + l4 * 4);
            for (int nn = 0; nn < 4; nn++) acc[m][nn] = bias;
        }
    }
    for (int c = 0; c < 3; c++) {
        // cvt + write current c to xs (loads arrived during previous MFMA)
        for (int p = 0; p < 4; p++) {
            bf16x8 w;
            w[0] = (__bf16)pa[p].x; w[1] = (__bf16)pa[p].y;
            w[2] = (__bf16)pa[p].z; w[3] = (__bf16)pa[p].w;
            w[4] = (__bf16)pb[p].x; w[5] = (__bf16)pb[p].y;
            w[6] = (__bf16)pb[p].z; w[7] = (__bf16)pb[p].w;
            int s = p * 16 + sp;
            int off = (s * 256 + (tid & 15) * 16) ^ ((s & 7) << 4);
            *(bf16x8*)(xs + off) = w;
        }
        // issue next-c row loads; latency hides under this c's MFMA phase
        if (c < 2) {
            const float* tbl = (c == 0) ? rel : ent;
            for (int p = 0; p < 4; p++) {
                const float* src = tbl + rows[c + 1][p] * EMBED + scol;
                pa[p] = *(const float4*)src;
                pb[p] = *(const float4*)(src + 4);
            }
        }
        __syncthreads();
        const __bf16* Wc = W1t + (wave * 64 + l15) * 384 + c * 128 + l4 * 8;
        __builtin_amdgcn_s_setprio(1);
        for (int kk = 0; kk < 4; kk++) {
            bf16x8 bfr[4];
            for (int nn = 0; nn < 4; nn++) {
                int s = nn * 16 + l15;
                int off = (s * 256 + kk * 64 + l4 * 16) ^ ((s & 7) << 4);
                bfr[nn] = *(const bf16x8*)(xs + off);
            }
            bf16x8 afr[4];
            for (int m = 0; m < 4; m++)
                afr[m] = *(const bf16x8*)(Wc + m * 16 * 384 + kk * 32);
            for (int m = 0; m < 4; m++)
                for (int nn = 0; nn < 4; nn++)
                    acc[m][nn] = __builtin_amdgcn_mfma_f32_16x16x32_bf16(
                        afr[m], bfr[nn], acc[m][nn], 0, 0, 0);
        }
        __builtin_amdgcn_s_setprio(0);
        __syncthreads();  // xs reads done; next c may overwrite
    }
    // write h1 (relu, bf16) to h1s
    for (int m = 0; m < 4; m++) {
        int f0 = wave * 64 + m * 16 + l4 * 4;
        for (int nn = 0; nn < 4; nn++) {
            int s = nn * 16 + l15;
            bf16x4 p;
            for (int j = 0; j < 4; j++) {
                float v = acc[m][nn][j];
                p[j] = (__bf16)(v > 0.f ? v : 0.f);
            }
            int off = (s * 512 + f0 * 2) ^ ((s & 7) << 4);
            *(bf16x4*)(h1s + off) = p;
        }
    }
    __syncthreads();

    // ================= Layer 2: h2 = relu(h1 @ W2 + b2) =================
    f32x4 acc2[4][4];
    {
        const int fb = wave * 64;
        for (int m = 0; m < 4; m++) {
            f32x4 bias = *(const f32x4*)(b2 + fb + m * 16 + l4 * 4);
            for (int nn = 0; nn < 4; nn++) acc2[m][nn] = bias;
        }
    }
    {
        const __bf16* Wc = W2t + (wave * 64 + l15) * 256 + l4 * 8;
        __builtin_amdgcn_s_setprio(1);
        for (int kk = 0; kk < 8; kk++) {
            bf16x8 bfr[4];
            for (int nn = 0; nn < 4; nn++) {
                int s = nn * 16 + l15;
                int off = (s * 512 + kk * 64 + l4 * 16) ^ ((s & 7) << 4);
                bfr[nn] = *(const bf16x8*)(h1s + off);
            }
            bf16x8 afr[4];
            for (int m = 0; m < 4; m++)
                afr[m] = *(const bf16x8*)(Wc + m * 16 * 256 + kk * 32);
            for (int m = 0; m < 4; m++)
                for (int nn = 0; nn < 4; nn++)
                    acc2[m][nn] = __builtin_amdgcn_mfma_f32_16x16x32_bf16(
                        afr[m], bfr[nn], acc2[m][nn], 0, 0, 0);
        }
        __builtin_amdgcn_s_setprio(0);
    }
    __syncthreads();  // all layer-2 reads of h1s done; h2s overwrites h1s
    for (int m = 0; m < 4; m++) {
        int f0 = wave * 64 + m * 16 + l4 * 4;
        for (int nn = 0; nn < 4; nn++) {
            int s = nn * 16 + l15;
            bf16x4 p;
            for (int j = 0; j < 4; j++) {
                float v = acc2[m][nn][j];
                p[j] = (__bf16)(v > 0.f ? v : 0.f);
            }
            int off = (s * 512 + f0 * 2) ^ ((s & 7) << 4);
            *(bf16x4*)(h2s + off) = p;
        }
    }
    __syncthreads();

    // ================= Layer 3: enc = h2 @ W3 (bias deferred to head) ======
    f32x4 acc3[2][4];
    for (int m = 0; m < 2; m++)
        for (int nn = 0; nn < 4; nn++)
            acc3[m][nn] = (f32x4)(0.f);
    {
        const __bf16* Wc = W3t + (wave * 32 + l15) * 256 + l4 * 8;
        __builtin_amdgcn_s_setprio(1);
        for (int kk = 0; kk < 8; kk++) {
            bf16x8 bfr[4];
            for (int nn = 0; nn < 4; nn++) {
                int s = nn * 16 + l15;
                int off = (s * 512 + kk * 64 + l4 * 16) ^ ((s & 7) << 4);
                bfr[nn] = *(const bf16x8*)(h2s + off);
            }
            bf16x8 afr[2];
            for (int m = 0; m < 2; m++)
                afr[m] = *(const bf16x8*)(Wc + m * 16 * 256 + kk * 32);
            for (int m = 0; m < 2; m++)
                for (int nn = 0; nn < 4; nn++)
                    acc3[m][nn] = __builtin_amdgcn_mfma_f32_16x16x32_bf16(
                        afr[m], bfr[nn], acc3[m][nn], 0, 0, 0);
        }
        __builtin_amdgcn_s_setprio(0);
    }
    // reduce over samples, accumulate into bucket
    {
        float* bucket = part + (blockIdx.x & (NBUCKET - 1)) * 128;
        for (int m = 0; m < 2; m++) {
            for (int j = 0; j < 4; j++) {
                float v = 0.f;
                for (int nn = 0; nn < 4; nn++) {
                    int g = s0 + nn * 16 + l15;
                    float t = acc3[m][nn][j];
                    v += (g < n) ? t : 0.f;
                }
                for (int off = 1; off < 16; off <<= 1) v += __shfl_xor(v, off);
                if (l15 == 0) {
                    int f = wave * 32 + m * 16 + l4 * 4 + j;
                    atomicAdd(bucket + f, v);
                }
            }
        }
    }
}

// ---- head: agg = sum/n + b3; out = relu(agg@Wf1+bf1)@Wf2+bf2 (f32) ----
__global__ void head_kernel(const float* __restrict__ part, const float* __restrict__ b3,
                            const float* __restrict__ Wf1, const float* __restrict__ bf1,
                            const float* __restrict__ Wf2, const float* __restrict__ bf2,
                            float* __restrict__ out, int n)
{
    __shared__ float agg[128];
    __shared__ float t[256];
    const int tid = threadIdx.x;
    if (tid < 128) {
        float s = 0.f;
        for (int b = 0; b < NBUCKET; b++) s += part[b * 128 + tid];
        agg[tid] = s / (float)n + b3[tid];
    }
    __syncthreads();
    {
        float a = bf1[tid];
        for (int k = 0; k < 128; k++) a += agg[k] * Wf1[k * 256 + tid];
        t[tid] = a > 0.f ? a : 0.f;
    }
    __syncthreads();
    if (tid < 128) {
        float o = bf2[tid];
        for (int i = 0; i < 256; i++) o += t[i] * Wf2[i * 128 + tid];
        out[tid] = o;
    }
}

extern "C" void kernel_launch(void* const* d_in, const int* in_sizes, int n_in,
                              void* d_out, int out_size, void* d_ws, size_t ws_size,
                              hipStream_t stream) {
    const int*   triples = (const int*)d_in[0];
    const float* ent     = (const float*)d_in[1];
    const float* rel     = (const float*)d_in[2];
    const float* W1      = (const float*)d_in[3];
    const float* b1      = (const float*)d_in[4];
    const float* W2      = (const float*)d_in[5];
    const float* b2      = (const float*)d_in[6];
    const float* W3      = (const float*)d_in[7];
    const float* b3      = (const float*)d_in[8];
    const float* Wf1     = (const float*)d_in[9];
    const float* bf1     = (const float*)d_in[10];
    const float* Wf2     = (const float*)d_in[11];
    const float* bf2     = (const float*)d_in[12];
    float* out = (float*)d_out;
    const int n = in_sizes[0] / 3;

    // ws layout (bytes): W1t[0,196608) W2t[196608,327680) W3t[327680,393216)
    //                    part[393216,458752)  — total 448 KB
    __bf16* W1t = (__bf16*)d_ws;
    __bf16* W2t = (__bf16*)((char*)d_ws + 196608);
    __bf16* W3t = (__bf16*)((char*)d_ws + 327680);
    float*  prt = (float*)((char*)d_ws + 393216);

    transpose_cvt<<<(384 * 256 + 255) / 256, 256, 0, stream>>>(W1, W1t, 384, 256);
    transpose_cvt<<<(256 * 256 + 255) / 256, 256, 0, stream>>>(W2, W2t, 256, 256);
    transpose_cvt<<<(256 * 128 + 255) / 256, 256, 0, stream>>>(W3, W3t, 256, 128);
    hipMemsetAsync(prt, 0, NBUCKET * 128 * sizeof(float), stream);

    const int blocks = (n + BM - 1) / BM;
    mlp_main<<<blocks, 256, 0, stream>>>(triples, ent, rel, W1t, b1, W2t, b2, W3t, prt, n);
    head_kernel<<<1, 256, 0, stream>>>(prt, b3, Wf1, bf1, Wf2, bf2, out, n);
}

// Round 3
// 717.931 us; speedup vs baseline: 1.2063x; 1.0831x over previous
//
#include <hip/hip_runtime.h>
#include <hip/hip_bf16.h>

// StructuralEncoder: gather(3x128 f32) -> 384->256->256->128 MLP (relu,relu,linear)
// -> mean over 1M rows -> 128->256->128 head.
// R3: single-stage xs (all 3 chunks, 48KB), 3 barriers/block, packed contiguous
// weight fragments (1KB per 16x32 A-frag), h2 overlays xs region, setprio.

#define EMBED 128
#define BM 64
#define NBUCKET 128

typedef __bf16 bf16x8 __attribute__((ext_vector_type(8)));
typedef __bf16 bf16x4 __attribute__((ext_vector_type(4)));
typedef float f32x4 __attribute__((ext_vector_type(4)));

// pack W (K x N, row-major) into MFMA A-fragment tiles:
// pk[((mt*(K/32)+kt)*64 + l)*8 + j] = W[(kt*32+(l>>4)*8+j)*N + (mt*16+(l&15))]
__global__ void pack_cvt(const float* __restrict__ src, __bf16* __restrict__ dst,
                         int K, int N) {
    int e = blockIdx.x * 256 + threadIdx.x;
    if (e >= K * N) return;
    int j = e & 7;
    int l = (e >> 3) & 63;
    int tile = e >> 9;
    int KT = K >> 5;
    int kt = tile % KT;
    int mt = tile / KT;
    int k = kt * 32 + (l >> 4) * 8 + j;
    int nc = mt * 16 + (l & 15);
    dst[e] = (__bf16)src[k * N + nc];
}

// ---- main fused MLP over 64-row tiles ----
__global__ __launch_bounds__(256, 2) void mlp_main(
    const int* __restrict__ triples,
    const float* __restrict__ ent, const float* __restrict__ rel,
    const __bf16* __restrict__ W1p, const float* __restrict__ b1,
    const __bf16* __restrict__ W2p, const float* __restrict__ b2,
    const __bf16* __restrict__ W3p,
    float* __restrict__ part, int n)
{
    // LDS 80KB: xs [0,48K) = 64 rows x 768B (384 bf16), swizzled 16B chunks;
    //           h1s [48K,80K) = 64 x 512B; h2s overlays xs after B2.
    __shared__ unsigned char lds[81920];
    unsigned char* xs  = lds;
    unsigned char* h1s = lds + 49152;
    unsigned char* h2s = lds;

    const int tid  = threadIdx.x;
    const int wave = tid >> 6;
    const int lane = tid & 63;
    const int l15  = lane & 15;
    const int l4   = lane >> 4;
    const int s0   = blockIdx.x * BM;
    const int sp   = tid >> 4;   // sample subgroup for staging
    const int ch   = tid & 15;   // 16B bf16 chunk (8 floats) within a c-row

    // ---- prologue: triple indices, then issue ALL gather loads ----
    int rows[3][4];
#pragma unroll
    for (int p = 0; p < 4; p++) {
        int g = s0 + p * 16 + sp;
        const int* t = triples + (g < n ? g : 0) * 3;
        rows[0][p] = t[0]; rows[1][p] = t[1]; rows[2][p] = t[2];
    }
    float4 ga[3][4], gb[3][4];
#pragma unroll
    for (int c = 0; c < 3; c++) {
        const float* tbl = (c == 1) ? rel : ent;
#pragma unroll
        for (int p = 0; p < 4; p++) {
            const float* src = tbl + (long)rows[c][p] * EMBED + ch * 8;
            ga[c][p] = *(const float4*)src;
            gb[c][p] = *(const float4*)(src + 4);
        }
    }
    // cvt + write xs (row s: [e1|rel|e2], 768B, 16B-chunk XOR swizzle)
#pragma unroll
    for (int c = 0; c < 3; c++)
#pragma unroll
        for (int p = 0; p < 4; p++) {
            bf16x8 w;
            w[0] = (__bf16)ga[c][p].x; w[1] = (__bf16)ga[c][p].y;
            w[2] = (__bf16)ga[c][p].z; w[3] = (__bf16)ga[c][p].w;
            w[4] = (__bf16)gb[c][p].x; w[5] = (__bf16)gb[c][p].y;
            w[6] = (__bf16)gb[c][p].z; w[7] = (__bf16)gb[c][p].w;
            int s = p * 16 + sp;
            int off = (s * 768 + c * 256 + ch * 16) ^ ((s & 7) << 4);
            *(bf16x8*)(xs + off) = w;
        }
    __syncthreads();  // B1: xs ready

    // ================= Layer 1: h1 = relu(x @ W1 + b1), K=384 =============
    f32x4 acc[4][4];
    {
        const int fb = wave * 64;
#pragma unroll
        for (int m = 0; m < 4; m++) {
            f32x4 bias = *(const f32x4*)(b1 + fb + m * 16 + l4 * 4);
#pragma unroll
            for (int nn = 0; nn < 4; nn++) acc[m][nn] = bias;
        }
    }
    __builtin_amdgcn_s_setprio(1);
#pragma unroll
    for (int kk = 0; kk < 12; kk++) {
        bf16x8 bfr[4];
#pragma unroll
        for (int nn = 0; nn < 4; nn++) {
            int s = nn * 16 + l15;
            int off = (s * 768 + kk * 64 + l4 * 16) ^ ((s & 7) << 4);
            bfr[nn] = *(const bf16x8*)(xs + off);
        }
        bf16x8 afr[4];
#pragma unroll
        for (int m = 0; m < 4; m++)
            afr[m] = *(const bf16x8*)(W1p + ((wave * 4 + m) * 12 + kk) * 512 + lane * 8);
#pragma unroll
        for (int m = 0; m < 4; m++)
#pragma unroll
            for (int nn = 0; nn < 4; nn++)
                acc[m][nn] = __builtin_amdgcn_mfma_f32_16x16x32_bf16(
                    afr[m], bfr[nn], acc[m][nn], 0, 0, 0);
    }
    __builtin_amdgcn_s_setprio(0);
    // write h1 (relu, bf16) to h1s
#pragma unroll
    for (int m = 0; m < 4; m++) {
        int f0 = wave * 64 + m * 16 + l4 * 4;
#pragma unroll
        for (int nn = 0; nn < 4; nn++) {
            int s = nn * 16 + l15;
            bf16x4 p;
#pragma unroll
            for (int j = 0; j < 4; j++) {
                float v = acc[m][nn][j];
                p[j] = (__bf16)(v > 0.f ? v : 0.f);
            }
            int off = (s * 512 + f0 * 2) ^ ((s & 7) << 4);
            *(bf16x4*)(h1s + off) = p;
        }
    }
    __syncthreads();  // B2: h1 ready; xs dead (h2 may overwrite)

    // ================= Layer 2: h2 = relu(h1 @ W2 + b2), K=256 ============
    f32x4 acc2[4][4];
    {
        const int fb = wave * 64;
#pragma unroll
        for (int m = 0; m < 4; m++) {
            f32x4 bias = *(const f32x4*)(b2 + fb + m * 16 + l4 * 4);
#pragma unroll
            for (int nn = 0; nn < 4; nn++) acc2[m][nn] = bias;
        }
    }
    __builtin_amdgcn_s_setprio(1);
#pragma unroll
    for (int kk = 0; kk < 8; kk++) {
        bf16x8 bfr[4];
#pragma unroll
        for (int nn = 0; nn < 4; nn++) {
            int s = nn * 16 + l15;
            int off = (s * 512 + kk * 64 + l4 * 16) ^ ((s & 7) << 4);
            bfr[nn] = *(const bf16x8*)(h1s + off);
        }
        bf16x8 afr[4];
#pragma unroll
        for (int m = 0; m < 4; m++)
            afr[m] = *(const bf16x8*)(W2p + ((wave * 4 + m) * 8 + kk) * 512 + lane * 8);
#pragma unroll
        for (int m = 0; m < 4; m++)
#pragma unroll
            for (int nn = 0; nn < 4; nn++)
                acc2[m][nn] = __builtin_amdgcn_mfma_f32_16x16x32_bf16(
                    afr[m], bfr[nn], acc2[m][nn], 0, 0, 0);
    }
    __builtin_amdgcn_s_setprio(0);
    // write h2 (relu, bf16) into xs region
#pragma unroll
    for (int m = 0; m < 4; m++) {
        int f0 = wave * 64 + m * 16 + l4 * 4;
#pragma unroll
        for (int nn = 0; nn < 4; nn++) {
            int s = nn * 16 + l15;
            bf16x4 p;
#pragma unroll
            for (int j = 0; j < 4; j++) {
                float v = acc2[m][nn][j];
                p[j] = (__bf16)(v > 0.f ? v : 0.f);
            }
            int off = (s * 512 + f0 * 2) ^ ((s & 7) << 4);
            *(bf16x4*)(h2s + off) = p;
        }
    }
    __syncthreads();  // B3: h2 ready

    // ================= Layer 3: enc = h2 @ W3 (bias in head), K=256 =======
    f32x4 acc3[2][4];
#pragma unroll
    for (int m = 0; m < 2; m++)
#pragma unroll
        for (int nn = 0; nn < 4; nn++)
            acc3[m][nn] = (f32x4)(0.f);
    __builtin_amdgcn_s_setprio(1);
#pragma unroll
    for (int kk = 0; kk < 8; kk++) {
        bf16x8 bfr[4];
#pragma unroll
        for (int nn = 0; nn < 4; nn++) {
            int s = nn * 16 + l15;
            int off = (s * 512 + kk * 64 + l4 * 16) ^ ((s & 7) << 4);
            bfr[nn] = *(const bf16x8*)(h2s + off);
        }
        bf16x8 afr[2];
#pragma unroll
        for (int m = 0; m < 2; m++)
            afr[m] = *(const bf16x8*)(W3p + ((wave * 2 + m) * 8 + kk) * 512 + lane * 8);
#pragma unroll
        for (int m = 0; m < 2; m++)
#pragma unroll
            for (int nn = 0; nn < 4; nn++)
                acc3[m][nn] = __builtin_amdgcn_mfma_f32_16x16x32_bf16(
                    afr[m], bfr[nn], acc3[m][nn], 0, 0, 0);
    }
    __builtin_amdgcn_s_setprio(0);
    // reduce over samples, accumulate into bucket
    {
        float* bucket = part + (blockIdx.x & (NBUCKET - 1)) * 128;
#pragma unroll
        for (int m = 0; m < 2; m++) {
#pragma unroll
            for (int j = 0; j < 4; j++) {
                float v = 0.f;
#pragma unroll
                for (int nn = 0; nn < 4; nn++) {
                    int g = s0 + nn * 16 + l15;
                    float t = acc3[m][nn][j];
                    v += (g < n) ? t : 0.f;
                }
                for (int off = 1; off < 16; off <<= 1) v += __shfl_xor(v, off);
                if (l15 == 0) {
                    int f = wave * 32 + m * 16 + l4 * 4 + j;
                    atomicAdd(bucket + f, v);
                }
            }
        }
    }
}

// ---- head: agg = sum/n + b3; out = relu(agg@Wf1+bf1)@Wf2+bf2 (f32) ----
__global__ void head_kernel(const float* __restrict__ part, const float* __restrict__ b3,
                            const float* __restrict__ Wf1, const float* __restrict__ bf1,
                            const float* __restrict__ Wf2, const float* __restrict__ bf2,
                            float* __restrict__ out, int n)
{
    __shared__ float agg[128];
    __shared__ float t[256];
    const int tid = threadIdx.x;
    if (tid < 128) {
        float s = 0.f;
        for (int b = 0; b < NBUCKET; b++) s += part[b * 128 + tid];
        agg[tid] = s / (float)n + b3[tid];
    }
    __syncthreads();
    {
        float a = bf1[tid];
        for (int k = 0; k < 128; k++) a += agg[k] * Wf1[k * 256 + tid];
        t[tid] = a > 0.f ? a : 0.f;
    }
    __syncthreads();
    if (tid < 128) {
        float o = bf2[tid];
        for (int i = 0; i < 256; i++) o += t[i] * Wf2[i * 128 + tid];
        out[tid] = o;
    }
}

extern "C" void kernel_launch(void* const* d_in, const int* in_sizes, int n_in,
                              void* d_out, int out_size, void* d_ws, size_t ws_size,
                              hipStream_t stream) {
    const int*   triples = (const int*)d_in[0];
    const float* ent     = (const float*)d_in[1];
    const float* rel     = (const float*)d_in[2];
    const float* W1      = (const float*)d_in[3];
    const float* b1      = (const float*)d_in[4];
    const float* W2      = (const float*)d_in[5];
    const float* b2      = (const float*)d_in[6];
    const float* W3      = (const float*)d_in[7];
    const float* b3      = (const float*)d_in[8];
    const float* Wf1     = (const float*)d_in[9];
    const float* bf1     = (const float*)d_in[10];
    const float* Wf2     = (const float*)d_in[11];
    const float* bf2     = (const float*)d_in[12];
    float* out = (float*)d_out;
    const int n = in_sizes[0] / 3;

    // ws layout (bytes): W1p[0,196608) W2p[196608,327680) W3p[327680,393216)
    //                    part[393216,458752)
    __bf16* W1p = (__bf16*)d_ws;
    __bf16* W2p = (__bf16*)((char*)d_ws + 196608);
    __bf16* W3p = (__bf16*)((char*)d_ws + 327680);
    float*  prt = (float*)((char*)d_ws + 393216);

    pack_cvt<<<(384 * 256 + 255) / 256, 256, 0, stream>>>(W1, W1p, 384, 256);
    pack_cvt<<<(256 * 256 + 255) / 256, 256, 0, stream>>>(W2, W2p, 256, 256);
    pack_cvt<<<(256 * 128 + 255) / 256, 256, 0, stream>>>(W3, W3p, 256, 128);
    hipMemsetAsync(prt, 0, NBUCKET * 128 * sizeof(float), stream);

    const int blocks = (n + BM - 1) / BM;
    mlp_main<<<blocks, 256, 0, stream>>>(triples, ent, rel, W1p, b1, W2p, b2, W3p, prt, n);
    head_kernel<<<1, 256, 0, stream>>>(prt, b3, Wf1, bf1, Wf2, bf2, out, n);
}

// Round 4
// 508.240 us; speedup vs baseline: 1.7040x; 1.4126x over previous
//
#include <hip/hip_runtime.h>
#include <hip/hip_bf16.h>

// StructuralEncoder: gather(3x128 f32) -> 384->256->256->128 MLP (relu,relu,linear)
// -> mean over 1M rows -> 128->256->128 head.
// R4: 48KB LDS via in-place reuse (xs -> h1 -> h2 all overlay [0,48K)),
// 5 barriers/block, 3 blocks/CU. Packed weight fragments, setprio, single-stage
// gather retained from R3.

#define EMBED 128
#define BM 64
#define NBUCKET 128

typedef __bf16 bf16x8 __attribute__((ext_vector_type(8)));
typedef __bf16 bf16x4 __attribute__((ext_vector_type(4)));
typedef float f32x4 __attribute__((ext_vector_type(4)));

// pack W (K x N, row-major) into MFMA A-fragment tiles:
// pk[((mt*(K/32)+kt)*64 + l)*8 + j] = W[(kt*32+(l>>4)*8+j)*N + (mt*16+(l&15))]
__global__ void pack_cvt(const float* __restrict__ src, __bf16* __restrict__ dst,
                         int K, int N) {
    int e = blockIdx.x * 256 + threadIdx.x;
    if (e >= K * N) return;
    int j = e & 7;
    int l = (e >> 3) & 63;
    int tile = e >> 9;
    int KT = K >> 5;
    int kt = tile % KT;
    int mt = tile / KT;
    int k = kt * 32 + (l >> 4) * 8 + j;
    int nc = mt * 16 + (l & 15);
    dst[e] = (__bf16)src[k * N + nc];
}

// ---- main fused MLP over 64-row tiles ----
__global__ __launch_bounds__(256, 3) void mlp_main(
    const int* __restrict__ triples,
    const float* __restrict__ ent, const float* __restrict__ rel,
    const __bf16* __restrict__ W1p, const float* __restrict__ b1,
    const __bf16* __restrict__ W2p, const float* __restrict__ b2,
    const __bf16* __restrict__ W3p,
    float* __restrict__ part, int n)
{
    // LDS 48KB, time-multiplexed:
    //   phase 1: xs  [0,48K) = 64 rows x 768B (384 bf16), 16B-chunk swizzle
    //   phase 2: h1s [0,32K) = 64 x 512B (after B2: all xs reads done)
    //   phase 3: h2s [0,32K) = 64 x 512B (after B4: all h1 reads done)
    __shared__ unsigned char lds[49152];
    unsigned char* xs  = lds;
    unsigned char* h1s = lds;
    unsigned char* h2s = lds;

    const int tid  = threadIdx.x;
    const int wave = tid >> 6;
    const int lane = tid & 63;
    const int l15  = lane & 15;
    const int l4   = lane >> 4;
    const int s0   = blockIdx.x * BM;
    const int sp   = tid >> 4;   // sample subgroup for staging
    const int ch   = tid & 15;   // 16B bf16 chunk (8 floats) within a c-row

    // ---- prologue: triple indices, then issue ALL gather loads ----
    int rows[3][4];
#pragma unroll
    for (int p = 0; p < 4; p++) {
        int g = s0 + p * 16 + sp;
        const int* t = triples + (g < n ? g : 0) * 3;
        rows[0][p] = t[0]; rows[1][p] = t[1]; rows[2][p] = t[2];
    }
    float4 ga[3][4], gb[3][4];
#pragma unroll
    for (int c = 0; c < 3; c++) {
        const float* tbl = (c == 1) ? rel : ent;
#pragma unroll
        for (int p = 0; p < 4; p++) {
            const float* src = tbl + (long)rows[c][p] * EMBED + ch * 8;
            ga[c][p] = *(const float4*)src;
            gb[c][p] = *(const float4*)(src + 4);
        }
    }
    // cvt + write xs (row s: [e1|rel|e2], 768B, 16B-chunk XOR swizzle)
#pragma unroll
    for (int c = 0; c < 3; c++)
#pragma unroll
        for (int p = 0; p < 4; p++) {
            bf16x8 w;
            w[0] = (__bf16)ga[c][p].x; w[1] = (__bf16)ga[c][p].y;
            w[2] = (__bf16)ga[c][p].z; w[3] = (__bf16)ga[c][p].w;
            w[4] = (__bf16)gb[c][p].x; w[5] = (__bf16)gb[c][p].y;
            w[6] = (__bf16)gb[c][p].z; w[7] = (__bf16)gb[c][p].w;
            int s = p * 16 + sp;
            int off = (s * 768 + c * 256 + ch * 16) ^ ((s & 7) << 4);
            *(bf16x8*)(xs + off) = w;
        }
    __syncthreads();  // B1: xs ready

    // ================= Layer 1: h1 = relu(x @ W1 + b1), K=384 =============
    f32x4 acc[4][4];
    {
        const int fb = wave * 64;
#pragma unroll
        for (int m = 0; m < 4; m++) {
            f32x4 bias = *(const f32x4*)(b1 + fb + m * 16 + l4 * 4);
#pragma unroll
            for (int nn = 0; nn < 4; nn++) acc[m][nn] = bias;
        }
    }
    __builtin_amdgcn_s_setprio(1);
#pragma unroll
    for (int kk = 0; kk < 12; kk++) {
        bf16x8 bfr[4];
#pragma unroll
        for (int nn = 0; nn < 4; nn++) {
            int s = nn * 16 + l15;
            int off = (s * 768 + kk * 64 + l4 * 16) ^ ((s & 7) << 4);
            bfr[nn] = *(const bf16x8*)(xs + off);
        }
        bf16x8 afr[4];
#pragma unroll
        for (int m = 0; m < 4; m++)
            afr[m] = *(const bf16x8*)(W1p + ((wave * 4 + m) * 12 + kk) * 512 + lane * 8);
#pragma unroll
        for (int m = 0; m < 4; m++)
#pragma unroll
            for (int nn = 0; nn < 4; nn++)
                acc[m][nn] = __builtin_amdgcn_mfma_f32_16x16x32_bf16(
                    afr[m], bfr[nn], acc[m][nn], 0, 0, 0);
    }
    __builtin_amdgcn_s_setprio(0);
    __syncthreads();  // B2: all xs reads done; h1 may overwrite region
    // write h1 (relu, bf16) to h1s
#pragma unroll
    for (int m = 0; m < 4; m++) {
        int f0 = wave * 64 + m * 16 + l4 * 4;
#pragma unroll
        for (int nn = 0; nn < 4; nn++) {
            int s = nn * 16 + l15;
            bf16x4 p;
#pragma unroll
            for (int j = 0; j < 4; j++) {
                float v = acc[m][nn][j];
                p[j] = (__bf16)(v > 0.f ? v : 0.f);
            }
            int off = (s * 512 + f0 * 2) ^ ((s & 7) << 4);
            *(bf16x4*)(h1s + off) = p;
        }
    }
    __syncthreads();  // B3: h1 ready

    // ================= Layer 2: h2 = relu(h1 @ W2 + b2), K=256 ============
    f32x4 acc2[4][4];
    {
        const int fb = wave * 64;
#pragma unroll
        for (int m = 0; m < 4; m++) {
            f32x4 bias = *(const f32x4*)(b2 + fb + m * 16 + l4 * 4);
#pragma unroll
            for (int nn = 0; nn < 4; nn++) acc2[m][nn] = bias;
        }
    }
    __builtin_amdgcn_s_setprio(1);
#pragma unroll
    for (int kk = 0; kk < 8; kk++) {
        bf16x8 bfr[4];
#pragma unroll
        for (int nn = 0; nn < 4; nn++) {
            int s = nn * 16 + l15;
            int off = (s * 512 + kk * 64 + l4 * 16) ^ ((s & 7) << 4);
            bfr[nn] = *(const bf16x8*)(h1s + off);
        }
        bf16x8 afr[4];
#pragma unroll
        for (int m = 0; m < 4; m++)
            afr[m] = *(const bf16x8*)(W2p + ((wave * 4 + m) * 8 + kk) * 512 + lane * 8);
#pragma unroll
        for (int m = 0; m < 4; m++)
#pragma unroll
            for (int nn = 0; nn < 4; nn++)
                acc2[m][nn] = __builtin_amdgcn_mfma_f32_16x16x32_bf16(
                    afr[m], bfr[nn], acc2[m][nn], 0, 0, 0);
    }
    __builtin_amdgcn_s_setprio(0);
    __syncthreads();  // B4: all h1 reads done; h2 may overwrite region
    // write h2 (relu, bf16)
#pragma unroll
    for (int m = 0; m < 4; m++) {
        int f0 = wave * 64 + m * 16 + l4 * 4;
#pragma unroll
        for (int nn = 0; nn < 4; nn++) {
            int s = nn * 16 + l15;
            bf16x4 p;
#pragma unroll
            for (int j = 0; j < 4; j++) {
                float v = acc2[m][nn][j];
                p[j] = (__bf16)(v > 0.f ? v : 0.f);
            }
            int off = (s * 512 + f0 * 2) ^ ((s & 7) << 4);
            *(bf16x4*)(h2s + off) = p;
        }
    }
    __syncthreads();  // B5: h2 ready

    // ================= Layer 3: enc = h2 @ W3 (bias in head), K=256 =======
    f32x4 acc3[2][4];
#pragma unroll
    for (int m = 0; m < 2; m++)
#pragma unroll
        for (int nn = 0; nn < 4; nn++)
            acc3[m][nn] = (f32x4)(0.f);
    __builtin_amdgcn_s_setprio(1);
#pragma unroll
    for (int kk = 0; kk < 8; kk++) {
        bf16x8 bfr[4];
#pragma unroll
        for (int nn = 0; nn < 4; nn++) {
            int s = nn * 16 + l15;
            int off = (s * 512 + kk * 64 + l4 * 16) ^ ((s & 7) << 4);
            bfr[nn] = *(const bf16x8*)(h2s + off);
        }
        bf16x8 afr[2];
#pragma unroll
        for (int m = 0; m < 2; m++)
            afr[m] = *(const bf16x8*)(W3p + ((wave * 2 + m) * 8 + kk) * 512 + lane * 8);
#pragma unroll
        for (int m = 0; m < 2; m++)
#pragma unroll
            for (int nn = 0; nn < 4; nn++)
                acc3[m][nn] = __builtin_amdgcn_mfma_f32_16x16x32_bf16(
                    afr[m], bfr[nn], acc3[m][nn], 0, 0, 0);
    }
    __builtin_amdgcn_s_setprio(0);
    // reduce over samples, accumulate into bucket
    {
        float* bucket = part + (blockIdx.x & (NBUCKET - 1)) * 128;
#pragma unroll
        for (int m = 0; m < 2; m++) {
#pragma unroll
            for (int j = 0; j < 4; j++) {
                float v = 0.f;
#pragma unroll
                for (int nn = 0; nn < 4; nn++) {
                    int g = s0 + nn * 16 + l15;
                    float t = acc3[m][nn][j];
                    v += (g < n) ? t : 0.f;
                }
                for (int off = 1; off < 16; off <<= 1) v += __shfl_xor(v, off);
                if (l15 == 0) {
                    int f = wave * 32 + m * 16 + l4 * 4 + j;
                    atomicAdd(bucket + f, v);
                }
            }
        }
    }
}

// ---- head: agg = sum/n + b3; out = relu(agg@Wf1+bf1)@Wf2+bf2 (f32) ----
__global__ void head_kernel(const float* __restrict__ part, const float* __restrict__ b3,
                            const float* __restrict__ Wf1, const float* __restrict__ bf1,
                            const float* __restrict__ Wf2, const float* __restrict__ bf2,
                            float* __restrict__ out, int n)
{
    __shared__ float agg[128];
    __shared__ float t[256];
    const int tid = threadIdx.x;
    if (tid < 128) {
        float s = 0.f;
        for (int b = 0; b < NBUCKET; b++) s += part[b * 128 + tid];
        agg[tid] = s / (float)n + b3[tid];
    }
    __syncthreads();
    {
        float a = bf1[tid];
        for (int k = 0; k < 128; k++) a += agg[k] * Wf1[k * 256 + tid];
        t[tid] = a > 0.f ? a : 0.f;
    }
    __syncthreads();
    if (tid < 128) {
        float o = bf2[tid];
        for (int i = 0; i < 256; i++) o += t[i] * Wf2[i * 128 + tid];
        out[tid] = o;
    }
}

extern "C" void kernel_launch(void* const* d_in, const int* in_sizes, int n_in,
                              void* d_out, int out_size, void* d_ws, size_t ws_size,
                              hipStream_t stream) {
    const int*   triples = (const int*)d_in[0];
    const float* ent     = (const float*)d_in[1];
    const float* rel     = (const float*)d_in[2];
    const float* W1      = (const float*)d_in[3];
    const float* b1      = (const float*)d_in[4];
    const float* W2      = (const float*)d_in[5];
    const float* b2      = (const float*)d_in[6];
    const float* W3      = (const float*)d_in[7];
    const float* b3      = (const float*)d_in[8];
    const float* Wf1     = (const float*)d_in[9];
    const float* bf1     = (const float*)d_in[10];
    const float* Wf2     = (const float*)d_in[11];
    const float* bf2     = (const float*)d_in[12];
    float* out = (float*)d_out;
    const int n = in_sizes[0] / 3;

    // ws layout (bytes): W1p[0,196608) W2p[196608,327680) W3p[327680,393216)
    //                    part[393216,458752)
    __bf16* W1p = (__bf16*)d_ws;
    __bf16* W2p = (__bf16*)((char*)d_ws + 196608);
    __bf16* W3p = (__bf16*)((char*)d_ws + 327680);
    float*  prt = (float*)((char*)d_ws + 393216);

    pack_cvt<<<(384 * 256 + 255) / 256, 256, 0, stream>>>(W1, W1p, 384, 256);
    pack_cvt<<<(256 * 256 + 255) / 256, 256, 0, stream>>>(W2, W2p, 256, 256);
    pack_cvt<<<(256 * 128 + 255) / 256, 256, 0, stream>>>(W3, W3p, 256, 128);
    hipMemsetAsync(prt, 0, NBUCKET * 128 * sizeof(float), stream);

    const int blocks = (n + BM - 1) / BM;
    mlp_main<<<blocks, 256, 0, stream>>>(triples, ent, rel, W1p, b1, W2p, b2, W3p, prt, n);
    head_kernel<<<1, 256, 0, stream>>>(prt, b3, Wf1, bf1, Wf2, bf2, out, n);
}